// Round 3
// baseline (188.662 us; speedup 1.0000x reference)
//
#include <hip/hip_runtime.h>
#include <hip/hip_bf16.h>

// Corr: B=4, C=256, H=W=64, HW=4096, TOPK=3, rat_s=0.05 -> sigma=3.2, 2*sigma^2=20.48
// s[m,n] = alpha * (1 - exp(-(dr^2+dc^2)/20.48)) * <xn_m, xn_n>  (symmetric)
// xc[m,n] = exp(2 s[m,n]) / (sm[m] sm[n]),  sm[m] = sum_n exp(s[m,n])
// out[b,k,col] = top-3 over m of xc[m,col]
//
// R1: XCD<->batch binding + triangular-symmetric rowsum.
// R2: log-domain top-k (select on key = 2s + ln(ism[row]); exp+ism[col] deferred
//     to merge) + per-wave 127-entry LDS mask table with compile-time ds_read
//     offsets -> epilogue ~6 VALU/element instead of ~18.

#define HW 4096
#define CDIM 256
#define INV2S2 0.048828125f  // 1/20.48
#define NEGINF -1e30f

typedef __bf16 bf16;
typedef __attribute__((ext_vector_type(8))) __bf16 bf16x8;
typedef __attribute__((ext_vector_type(4))) float f32x4;

#define GAS __attribute__((address_space(1)))
#define LAS __attribute__((address_space(3)))

__device__ __forceinline__ void ins3(float v, float& t0, float& t1, float& t2) {
    float m01 = fminf(t0, v);
    t0 = fmaxf(t0, v);
    float m12 = fminf(t1, m01);
    t1 = fmaxf(t1, m01);
    t2 = fmaxf(t2, m12);
}

// triangular decode: t = mt*(mt+1)/2 + nt, nt <= mt
__device__ __forceinline__ void decode_tri(int t, int& mt, int& nt) {
    int m = (int)((sqrtf(8.f * (float)t + 1.f) - 1.f) * 0.5f);
    while ((m + 1) * (m + 2) / 2 <= t) ++m;
    while (m * (m + 1) / 2 > t) --m;
    mt = m;
    nt = t - m * (m + 1) / 2;
}

// ---------------- normalize + transpose to bf16 xnT[b][pixel][channel] ----------------
__global__ __launch_bounds__(256) void corr_norm(const float* __restrict__ x,
                                                 bf16* __restrict__ xnT) {
    __shared__ float red[4][64];
    __shared__ float invn[64];
    int tid = threadIdx.x;
    int pl = tid & 63, cg = tid >> 6;       // pixel-lane, channel-group
    int P = blockIdx.x * 64 + pl;           // flat index over b*HW
    int b = P >> 12;
    int pix = P & 4095;
    const float* xb = x + ((size_t)(b * CDIM + cg * 64) << 12) + pix;
    float v[64];
    float ss = 0.f;
#pragma unroll
    for (int j = 0; j < 64; ++j) {
        v[j] = xb[(size_t)j << 12];
        ss += v[j] * v[j];
    }
    red[cg][pl] = ss;
    __syncthreads();
    if (tid < 64) {
        float s = red[0][tid] + red[1][tid] + red[2][tid] + red[3][tid];
        invn[tid] = 1.0f / fmaxf(sqrtf(s), 1e-12f);
    }
    __syncthreads();
    float inv = invn[pl];
    bf16* o = xnT + (size_t)P * CDIM + cg * 64;
#pragma unroll
    for (int j0 = 0; j0 < 64; j0 += 8) {
        bf16x8 pk;
#pragma unroll
        for (int j = 0; j < 8; ++j) pk[j] = (bf16)(v[j0 + j] * inv);
        *(bf16x8*)(o + j0) = pk;
    }
}

// ---------------- shared GEMM tile core: 128x128 tile, K=256, 4 waves 2x2 ----------------
__device__ __forceinline__ void gemm_tile(const bf16* __restrict__ xb, int mbase, int nbase,
                                          bf16* As, bf16* Bs, f32x4 (&acc)[4][4]) {
    const int tid = threadIdx.x;
    const int wave = tid >> 6;
    const int lane = tid & 63;
    const int wm = wave >> 1, wn = wave & 1;
    const int l15 = lane & 15, quad = lane >> 4;
#pragma unroll
    for (int mi = 0; mi < 4; ++mi)
#pragma unroll
        for (int ni = 0; ni < 4; ++ni) acc[mi][ni] = (f32x4)0.f;

    for (int k0 = 0; k0 < CDIM; k0 += 32) {
#pragma unroll
        for (int r = 0; r < 2; ++r) {
            int idx = r * 256 + tid;
            int prow = idx >> 2, sub = idx & 3;
            const bf16* gA = xb + ((size_t)(mbase + prow) << 8) + k0 + (sub << 3);
            const bf16* gB = xb + ((size_t)(nbase + prow) << 8) + k0 + (sub << 3);
            bf16* lA = As + ((r * 4 + wave) << 9);  // wave-uniform base, lane*16B appended by HW
            bf16* lB = Bs + ((r * 4 + wave) << 9);
            __builtin_amdgcn_global_load_lds((const GAS void*)gA, (LAS void*)lA, 16, 0, 0);
            __builtin_amdgcn_global_load_lds((const GAS void*)gB, (LAS void*)lB, 16, 0, 0);
        }
        __syncthreads();
        bf16x8 af[4], bfr[4];
#pragma unroll
        for (int i = 0; i < 4; ++i) {
            af[i]  = *(const bf16x8*)(As + (wm * 64 + i * 16 + l15) * 32 + quad * 8);
            bfr[i] = *(const bf16x8*)(Bs + (wn * 64 + i * 16 + l15) * 32 + quad * 8);
        }
#pragma unroll
        for (int mi = 0; mi < 4; ++mi)
#pragma unroll
            for (int ni = 0; ni < 4; ++ni)
                acc[mi][ni] = __builtin_amdgcn_mfma_f32_16x16x32_bf16(af[mi], bfr[ni],
                                                                      acc[mi][ni], 0, 0, 0);
        __syncthreads();
    }
}

// build per-wave extended mask table: ext[wave][j] = scale*(1 - exp(-(adr^2+(j-63)^2)/20.48))
// j in [0,127]; adr = wave's |image-row(m) - image-row(n)| distance.
__device__ __forceinline__ void build_ext(float (&ext)[4][128], int wave, int lane, int adr,
                                          float scale) {
    float fr2 = (float)(adr * adr);
#pragma unroll
    for (int h = 0; h < 2; ++h) {
        int j = lane + h * 64;
        float d = (float)(j - 63);
        ext[wave][j] = scale * (1.f - __expf(-(fr2 + d * d) * INV2S2));
    }
}

// ---------------- pass B: rowsum of exp(s), triangular tiles, dual accumulation ----------------
__global__ __launch_bounds__(256) void corr_rowsum(const bf16* __restrict__ xnT,
                                                   const float* __restrict__ alpha_p,
                                                   float* __restrict__ sm) {
    __shared__ __align__(16) bf16 As[128 * 32];
    __shared__ __align__(16) bf16 Bs[128 * 32];
    __shared__ float ext[4][128];
    int tid = threadIdx.x;
    // XCD binding: linear dispatch id % 8 = XCD (round-robin). 2 XCDs per batch.
    int lin = blockIdx.x;
    int xcd = lin & 7;
    int b = xcd >> 1;
    int t = ((lin >> 3) << 1) + (xcd & 1);  // [0, 528)
    int mt, nt;
    decode_tri(t, mt, nt);
    int mbase = mt * 128, nbase = nt * 128;
    int wave = tid >> 6, lane = tid & 63;
    int wm = wave >> 1, wn = wave & 1, l15 = lane & 15, quad = lane >> 4;
    int rowi = (mbase + wm * 64) >> 6;
    int coli = (nbase + wn * 64) >> 6;
    int adr = rowi - coli; if (adr < 0) adr = -adr;
    build_ext(ext, wave, lane, adr, alpha_p[0]);  // scale = alpha

    f32x4 acc[4][4];
    gemm_tile(xnT + ((size_t)b << 20), mbase, nbase, As, Bs, acc);

    // per-lane base into ext: index = 63 + (mi-ni)*16 + r + quad*4 - l15
    const float* extw = &ext[wave][15 + quad * 4 - l15];  // +48+(mi-ni)*16+r at use
    float colpart[4] = {0.f, 0.f, 0.f, 0.f};
#pragma unroll
    for (int mi = 0; mi < 4; ++mi) {
#pragma unroll
        for (int r = 0; r < 4; ++r) {
            float ssum = 0.f;
#pragma unroll
            for (int ni = 0; ni < 4; ++ni) {
                float s = extw[48 + (mi - ni) * 16 + r] * acc[mi][ni][r];
                float e = __expf(s);
                ssum += e;
                colpart[ni] += e;
            }
            ssum += __shfl_xor(ssum, 1);
            ssum += __shfl_xor(ssum, 2);
            ssum += __shfl_xor(ssum, 4);
            ssum += __shfl_xor(ssum, 8);
            if (l15 == 0)
                atomicAdd(&sm[(b << 12) + mbase + wm * 64 + mi * 16 + quad * 4 + r], ssum);
        }
    }
    if (mt != nt) {
        // column sums = row sums of the transposed (sub-diagonal) tile
#pragma unroll
        for (int ni = 0; ni < 4; ++ni) {
            float c = colpart[ni];
            c += __shfl_xor(c, 16);
            c += __shfl_xor(c, 32);
            if (quad == 0)
                atomicAdd(&sm[(b << 12) + nbase + wn * 64 + ni * 16 + l15], c);
        }
    }
}

// ---------------- reciprocal + negative log ----------------
__global__ __launch_bounds__(256) void corr_recip(const float* __restrict__ sm,
                                                  float* __restrict__ ism,
                                                  float* __restrict__ lsm) {
    int i = blockIdx.x * 256 + threadIdx.x;
    if (i < 4 * HW) {
        float s = sm[i];
        ism[i] = 1.0f / s;
        lsm[i] = -__logf(s);
    }
}

// ---------------- pass C: log-domain per-tile column top-3 (full grid, XCD-bound) ----------------
__global__ __launch_bounds__(256) void corr_topk(const bf16* __restrict__ xnT,
                                                 const float* __restrict__ alpha_p,
                                                 const float* __restrict__ lsm,
                                                 float* __restrict__ wtop) {
    __shared__ __align__(16) bf16 As[128 * 32];
    __shared__ __align__(16) bf16 Bs[128 * 32];
    __shared__ float ext[4][128];
    __shared__ float mbuf[2][128][3];
    int tid = threadIdx.x;
    // XCD binding: lin%8 -> XCD; batch = xcd>>1; tile index mtile-major (A-tile reuse).
    int lin = blockIdx.x;
    int xcd = lin & 7;
    int b = xcd >> 1;
    int t = ((lin >> 3) << 1) + (xcd & 1);  // [0, 1024)
    int mtile = t >> 5, ntile = t & 31;
    int mbase = mtile * 128, nbase = ntile * 128;
    int wave = tid >> 6, lane = tid & 63;
    int wm = wave >> 1, wn = wave & 1, l15 = lane & 15, quad = lane >> 4;
    int rowi = (mbase + wm * 64) >> 6;
    int coli = (nbase + wn * 64) >> 6;
    int adr = rowi - coli; if (adr < 0) adr = -adr;
    build_ext(ext, wave, lane, adr, 2.0f * alpha_p[0]);  // scale = 2*alpha

    f32x4 acc[4][4];
    gemm_tile(xnT + ((size_t)b << 20), mbase, nbase, As, Bs, acc);

    float lr[4][4];
#pragma unroll
    for (int mi = 0; mi < 4; ++mi)
#pragma unroll
        for (int r = 0; r < 4; ++r)
            lr[mi][r] = lsm[(b << 12) + mbase + wm * 64 + mi * 16 + quad * 4 + r];
    const float* extw = &ext[wave][15 + quad * 4 - l15];
#pragma unroll
    for (int ni = 0; ni < 4; ++ni) {
        float t0 = NEGINF, t1 = NEGINF, t2 = NEGINF;
#pragma unroll
        for (int mi = 0; mi < 4; ++mi) {
#pragma unroll
            for (int r = 0; r < 4; ++r) {
                float key = fmaf(extw[48 + (mi - ni) * 16 + r], acc[mi][ni][r], lr[mi][r]);
                ins3(key, t0, t1, t2);
            }
        }
        // merge the 4 quads (disjoint row sets, same column)
#pragma unroll
        for (int d = 16; d <= 32; d <<= 1) {
            float s0 = __shfl_xor(t0, d);
            float s1 = __shfl_xor(t1, d);
            float s2 = __shfl_xor(t2, d);
            ins3(s0, t0, t1, t2);
            ins3(s1, t0, t1, t2);
            ins3(s2, t0, t1, t2);
        }
        if (quad == 0) {
            int cl = wn * 64 + ni * 16 + l15;
            mbuf[wm][cl][0] = t0;
            mbuf[wm][cl][1] = t1;
            mbuf[wm][cl][2] = t2;
        }
    }
    __syncthreads();
    if (tid < 128) {
        float t0 = mbuf[0][tid][0], t1 = mbuf[0][tid][1], t2 = mbuf[0][tid][2];
        ins3(mbuf[1][tid][0], t0, t1, t2);
        ins3(mbuf[1][tid][1], t0, t1, t2);
        ins3(mbuf[1][tid][2], t0, t1, t2);
        size_t o = (((size_t)(b * 32 + mtile) << 12) + nbase + tid) * 3;
        wtop[o] = t0;
        wtop[o + 1] = t1;
        wtop[o + 2] = t2;
    }
}

// ---------------- final merge of 32 m-tile key-partials; exp + column scale ----------------
__global__ __launch_bounds__(256) void corr_merge(const float* __restrict__ wtop,
                                                  const float* __restrict__ ism,
                                                  float* __restrict__ out) {
    int idx = blockIdx.x * 256 + threadIdx.x;
    if (idx >= 4 * HW) return;
    int b = idx >> 12, col = idx & 4095;
    float t0 = NEGINF, t1 = NEGINF, t2 = NEGINF;
    for (int mt = 0; mt < 32; ++mt) {
        const float* q = wtop + (((size_t)(b * 32 + mt) << 12) + col) * 3;
        ins3(q[0], t0, t1, t2);
        ins3(q[1], t0, t1, t2);
        ins3(q[2], t0, t1, t2);
    }
    float ismc = ism[idx];
    out[((b * 3 + 0) << 12) + col] = __expf(t0) * ismc;
    out[((b * 3 + 1) << 12) + col] = __expf(t1) * ismc;
    out[((b * 3 + 2) << 12) + col] = __expf(t2) * ismc;
}

extern "C" void kernel_launch(void* const* d_in, const int* in_sizes, int n_in,
                              void* d_out, int out_size, void* d_ws, size_t ws_size,
                              hipStream_t stream) {
    const float* x = (const float*)d_in[0];
    const float* alpha = (const float*)d_in[1];
    float* out = (float*)d_out;
    char* ws = (char*)d_ws;
    bf16* xnT = (bf16*)ws;                                    // 8 MB
    float* sm = (float*)(ws + (8u << 20));                    // 64 KB
    float* ism = (float*)(ws + (8u << 20) + (64u << 10));     // 64 KB
    float* lsm = (float*)(ws + (8u << 20) + (128u << 10));    // 64 KB
    float* wtop = (float*)(ws + (8u << 20) + (192u << 10));   // 6 MB

    hipMemsetAsync(sm, 0, 4 * HW * sizeof(float), stream);
    corr_norm<<<256, 256, 0, stream>>>(x, xnT);
    corr_rowsum<<<528 * 4, 256, 0, stream>>>(xnT, alpha, sm);
    corr_recip<<<64, 256, 0, stream>>>(sm, ism, lsm);
    corr_topk<<<1024 * 4, 256, 0, stream>>>(xnT, alpha, lsm, wtop);
    corr_merge<<<64, 256, 0, stream>>>(wtop, ism, out);
}

// Round 4
// 165.218 us; speedup vs baseline: 1.1419x; 1.1419x over previous
//
#include <hip/hip_runtime.h>
#include <hip/hip_bf16.h>

// Corr: B=4, C=256, H=W=64, HW=4096, TOPK=3, rat_s=0.05 -> sigma=3.2, 2*sigma^2=20.48
// s[m,n] = alpha * (1 - exp(-(dr^2+dc^2)/20.48)) * <xn_m, xn_n>  (symmetric)
// xc[m,n] = exp(2 s[m,n]) / (sm[m] sm[n]),  sm[m] = sum_n exp(s[m,n])
// out[b,k,col] = top-3 over m of xc[m,col]
//
// R1: XCD<->batch binding + triangular-symmetric rowsum.
// R2: log-domain top-k + per-wave 127-entry LDS mask table.
// R3: (a) rowsum atomics -> per-tile non-atomic partial vectors + slot-reduce in
//     recip (atomics were write-through to HBM: 10.4MB WRITE_SIZE, serializing);
//     (b) single-barrier double-buffered K-loop (global_load_lds overlaps the
//     previous iteration's MFMA; barrier count halved).

#define HW 4096
#define CDIM 256
#define INV2S2 0.048828125f  // 1/20.48
#define NEGINF -1e30f

typedef __bf16 bf16;
typedef __attribute__((ext_vector_type(8))) __bf16 bf16x8;
typedef __attribute__((ext_vector_type(4))) float f32x4;

#define GAS __attribute__((address_space(1)))
#define LAS __attribute__((address_space(3)))

__device__ __forceinline__ void ins3(float v, float& t0, float& t1, float& t2) {
    float m01 = fminf(t0, v);
    t0 = fmaxf(t0, v);
    float m12 = fminf(t1, m01);
    t1 = fmaxf(t1, m01);
    t2 = fmaxf(t2, m12);
}

// triangular decode: t = mt*(mt+1)/2 + nt, nt <= mt
__device__ __forceinline__ void decode_tri(int t, int& mt, int& nt) {
    int m = (int)((sqrtf(8.f * (float)t + 1.f) - 1.f) * 0.5f);
    while ((m + 1) * (m + 2) / 2 <= t) ++m;
    while (m * (m + 1) / 2 > t) --m;
    mt = m;
    nt = t - m * (m + 1) / 2;
}

// ---------------- normalize + transpose to bf16 xnT[b][pixel][channel] ----------------
__global__ __launch_bounds__(256) void corr_norm(const float* __restrict__ x,
                                                 bf16* __restrict__ xnT) {
    __shared__ float red[4][64];
    __shared__ float invn[64];
    int tid = threadIdx.x;
    int pl = tid & 63, cg = tid >> 6;       // pixel-lane, channel-group
    int P = blockIdx.x * 64 + pl;           // flat index over b*HW
    int b = P >> 12;
    int pix = P & 4095;
    const float* xb = x + ((size_t)(b * CDIM + cg * 64) << 12) + pix;
    float v[64];
    float ss = 0.f;
#pragma unroll
    for (int j = 0; j < 64; ++j) {
        v[j] = xb[(size_t)j << 12];
        ss += v[j] * v[j];
    }
    red[cg][pl] = ss;
    __syncthreads();
    if (tid < 64) {
        float s = red[0][tid] + red[1][tid] + red[2][tid] + red[3][tid];
        invn[tid] = 1.0f / fmaxf(sqrtf(s), 1e-12f);
    }
    __syncthreads();
    float inv = invn[pl];
    bf16* o = xnT + (size_t)P * CDIM + cg * 64;
#pragma unroll
    for (int j0 = 0; j0 < 64; j0 += 8) {
        bf16x8 pk;
#pragma unroll
        for (int j = 0; j < 8; ++j) pk[j] = (bf16)(v[j0 + j] * inv);
        *(bf16x8*)(o + j0) = pk;
    }
}

// ---------------- GEMM tile core: 128x128, K=256, double-buffered single-barrier ----------------
__device__ __forceinline__ void gemm_tile(const bf16* __restrict__ xb, int mbase, int nbase,
                                          bf16* As, bf16* Bs, f32x4 (&acc)[4][4]) {
    const int tid = threadIdx.x;
    const int wave = tid >> 6;
    const int lane = tid & 63;
    const int wm = wave >> 1, wn = wave & 1;
    const int l15 = lane & 15, quad = lane >> 4;
#pragma unroll
    for (int mi = 0; mi < 4; ++mi)
#pragma unroll
        for (int ni = 0; ni < 4; ++ni) acc[mi][ni] = (f32x4)0.f;

    auto issue = [&](int kk, int buf) {
#pragma unroll
        for (int r = 0; r < 2; ++r) {
            int idx = r * 256 + tid;
            int prow = idx >> 2, sub = idx & 3;
            const bf16* gA = xb + ((size_t)(mbase + prow) << 8) + kk * 32 + (sub << 3);
            const bf16* gB = xb + ((size_t)(nbase + prow) << 8) + kk * 32 + (sub << 3);
            bf16* lA = As + buf * 4096 + ((r * 4 + wave) << 9);  // wave-uniform base
            bf16* lB = Bs + buf * 4096 + ((r * 4 + wave) << 9);
            __builtin_amdgcn_global_load_lds((const GAS void*)gA, (LAS void*)lA, 16, 0, 0);
            __builtin_amdgcn_global_load_lds((const GAS void*)gB, (LAS void*)lB, 16, 0, 0);
        }
    };
    issue(0, 0);
#pragma unroll
    for (int kk = 0; kk < 8; ++kk) {
        __syncthreads();  // drains buf[kk&1] loads (vmcnt) + prev ds_reads (lgkm)
        if (kk < 7) issue(kk + 1, (kk + 1) & 1);  // overlaps with this iter's MFMA
        int buf = kk & 1;
        bf16x8 af[4], bfr[4];
#pragma unroll
        for (int i = 0; i < 4; ++i) {
            af[i]  = *(const bf16x8*)(As + buf * 4096 + (wm * 64 + i * 16 + l15) * 32 + quad * 8);
            bfr[i] = *(const bf16x8*)(Bs + buf * 4096 + (wn * 64 + i * 16 + l15) * 32 + quad * 8);
        }
#pragma unroll
        for (int mi = 0; mi < 4; ++mi)
#pragma unroll
            for (int ni = 0; ni < 4; ++ni)
                acc[mi][ni] = __builtin_amdgcn_mfma_f32_16x16x32_bf16(af[mi], bfr[ni],
                                                                      acc[mi][ni], 0, 0, 0);
    }
}

// build per-wave extended mask table: ext[wave][j] = scale*(1 - exp(-(adr^2+(j-63)^2)/20.48))
__device__ __forceinline__ void build_ext(float (&ext)[4][128], int wave, int lane, int adr,
                                          float scale) {
    float fr2 = (float)(adr * adr);
#pragma unroll
    for (int h = 0; h < 2; ++h) {
        int j = lane + h * 64;
        float d = (float)(j - 63);
        ext[wave][j] = scale * (1.f - __expf(-(fr2 + d * d) * INV2S2));
    }
}

// ---------------- pass B: rowsum partials, triangular tiles, no atomics ----------------
// rpart[((b*32 + strip)*32 + slot)*128 + j]: strip s gets row-sums from tiles (s, nt<=s)
// at slot nt, and col-sums from tiles (mt>s, s) at slot mt. Every slot written once.
__global__ __launch_bounds__(256) void corr_rowsum(const bf16* __restrict__ xnT,
                                                   const float* __restrict__ alpha_p,
                                                   float* __restrict__ rpart) {
    __shared__ __align__(16) bf16 As[2 * 128 * 32];
    __shared__ __align__(16) bf16 Bs[2 * 128 * 32];
    __shared__ float ext[4][128];
    __shared__ float rbuf[2][128];  // [wn][row]
    __shared__ float cbuf[2][128];  // [wm][col]
    int tid = threadIdx.x;
    int lin = blockIdx.x;
    int xcd = lin & 7;
    int b = xcd >> 1;
    int t = ((lin >> 3) << 1) + (xcd & 1);  // [0, 528)
    int mt, nt;
    decode_tri(t, mt, nt);
    int mbase = mt * 128, nbase = nt * 128;
    int wave = tid >> 6, lane = tid & 63;
    int wm = wave >> 1, wn = wave & 1, l15 = lane & 15, quad = lane >> 4;
    int rowi = (mbase + wm * 64) >> 6;
    int coli = (nbase + wn * 64) >> 6;
    int adr = rowi - coli; if (adr < 0) adr = -adr;
    build_ext(ext, wave, lane, adr, alpha_p[0]);  // wave-private: no barrier needed

    f32x4 acc[4][4];
    gemm_tile(xnT + ((size_t)b << 20), mbase, nbase, As, Bs, acc);

    const float* extw = &ext[wave][15 + quad * 4 - l15];
    float colpart[4] = {0.f, 0.f, 0.f, 0.f};
#pragma unroll
    for (int mi = 0; mi < 4; ++mi) {
#pragma unroll
        for (int r = 0; r < 4; ++r) {
            float ssum = 0.f;
#pragma unroll
            for (int ni = 0; ni < 4; ++ni) {
                float s = extw[48 + (mi - ni) * 16 + r] * acc[mi][ni][r];
                float e = __expf(s);
                ssum += e;
                colpart[ni] += e;
            }
            ssum += __shfl_xor(ssum, 1);
            ssum += __shfl_xor(ssum, 2);
            ssum += __shfl_xor(ssum, 4);
            ssum += __shfl_xor(ssum, 8);
            if (l15 == 0) rbuf[wn][wm * 64 + mi * 16 + quad * 4 + r] = ssum;
        }
    }
#pragma unroll
    for (int ni = 0; ni < 4; ++ni) {
        float c = colpart[ni];
        c += __shfl_xor(c, 16);
        c += __shfl_xor(c, 32);
        if (quad == 0) cbuf[wm][wn * 64 + ni * 16 + l15] = c;
    }
    __syncthreads();
    if (tid < 128) {
        rpart[(size_t)((b * 32 + mt) * 32 + nt) * 128 + tid] = rbuf[0][tid] + rbuf[1][tid];
    } else if (mt != nt) {
        int j = tid - 128;
        rpart[(size_t)((b * 32 + nt) * 32 + mt) * 128 + j] = cbuf[0][j] + cbuf[1][j];
    }
}

// ---------------- slot-reduce + reciprocal + negative log ----------------
__global__ __launch_bounds__(256) void corr_recip(const float* __restrict__ rpart,
                                                  float* __restrict__ ism,
                                                  float* __restrict__ lsm) {
    int i = blockIdx.x * 256 + threadIdx.x;
    if (i >= 4 * HW) return;
    int b = i >> 12, gr = i & 4095, s = gr >> 7, j = gr & 127;
    const float* base = rpart + (size_t)((b * 32 + s) * 32) * 128 + j;
    float sum = 0.f;
#pragma unroll
    for (int sl = 0; sl < 32; ++sl) sum += base[sl * 128];
    ism[i] = 1.0f / sum;
    lsm[i] = -__logf(sum);
}

// ---------------- pass C: log-domain per-tile column top-3 (full grid, XCD-bound) ----------------
__global__ __launch_bounds__(256) void corr_topk(const bf16* __restrict__ xnT,
                                                 const float* __restrict__ alpha_p,
                                                 const float* __restrict__ lsm,
                                                 float* __restrict__ wtop) {
    __shared__ __align__(16) bf16 As[2 * 128 * 32];
    __shared__ __align__(16) bf16 Bs[2 * 128 * 32];
    __shared__ float ext[4][128];
    __shared__ float mbuf[2][128][3];
    int tid = threadIdx.x;
    int lin = blockIdx.x;
    int xcd = lin & 7;
    int b = xcd >> 1;
    int t = ((lin >> 3) << 1) + (xcd & 1);  // [0, 1024)
    int mtile = t >> 5, ntile = t & 31;
    int mbase = mtile * 128, nbase = ntile * 128;
    int wave = tid >> 6, lane = tid & 63;
    int wm = wave >> 1, wn = wave & 1, l15 = lane & 15, quad = lane >> 4;
    int rowi = (mbase + wm * 64) >> 6;
    int coli = (nbase + wn * 64) >> 6;
    int adr = rowi - coli; if (adr < 0) adr = -adr;
    build_ext(ext, wave, lane, adr, 2.0f * alpha_p[0]);

    f32x4 acc[4][4];
    gemm_tile(xnT + ((size_t)b << 20), mbase, nbase, As, Bs, acc);

    float lr[4][4];
#pragma unroll
    for (int mi = 0; mi < 4; ++mi)
#pragma unroll
        for (int r = 0; r < 4; ++r)
            lr[mi][r] = lsm[(b << 12) + mbase + wm * 64 + mi * 16 + quad * 4 + r];
    const float* extw = &ext[wave][15 + quad * 4 - l15];
#pragma unroll
    for (int ni = 0; ni < 4; ++ni) {
        float t0 = NEGINF, t1 = NEGINF, t2 = NEGINF;
#pragma unroll
        for (int mi = 0; mi < 4; ++mi) {
#pragma unroll
            for (int r = 0; r < 4; ++r) {
                float key = fmaf(extw[48 + (mi - ni) * 16 + r], acc[mi][ni][r], lr[mi][r]);
                ins3(key, t0, t1, t2);
            }
        }
#pragma unroll
        for (int d = 16; d <= 32; d <<= 1) {
            float s0 = __shfl_xor(t0, d);
            float s1 = __shfl_xor(t1, d);
            float s2 = __shfl_xor(t2, d);
            ins3(s0, t0, t1, t2);
            ins3(s1, t0, t1, t2);
            ins3(s2, t0, t1, t2);
        }
        if (quad == 0) {
            int cl = wn * 64 + ni * 16 + l15;
            mbuf[wm][cl][0] = t0;
            mbuf[wm][cl][1] = t1;
            mbuf[wm][cl][2] = t2;
        }
    }
    __syncthreads();
    if (tid < 128) {
        float t0 = mbuf[0][tid][0], t1 = mbuf[0][tid][1], t2 = mbuf[0][tid][2];
        ins3(mbuf[1][tid][0], t0, t1, t2);
        ins3(mbuf[1][tid][1], t0, t1, t2);
        ins3(mbuf[1][tid][2], t0, t1, t2);
        size_t o = (((size_t)(b * 32 + mtile) << 12) + nbase + tid) * 3;
        wtop[o] = t0;
        wtop[o + 1] = t1;
        wtop[o + 2] = t2;
    }
}

// ---------------- final merge of 32 m-tile key-partials; exp + column scale ----------------
__global__ __launch_bounds__(256) void corr_merge(const float* __restrict__ wtop,
                                                  const float* __restrict__ ism,
                                                  float* __restrict__ out) {
    int idx = blockIdx.x * 256 + threadIdx.x;
    if (idx >= 4 * HW) return;
    int b = idx >> 12, col = idx & 4095;
    float t0 = NEGINF, t1 = NEGINF, t2 = NEGINF;
    for (int mt = 0; mt < 32; ++mt) {
        const float* q = wtop + (((size_t)(b * 32 + mt) << 12) + col) * 3;
        ins3(q[0], t0, t1, t2);
        ins3(q[1], t0, t1, t2);
        ins3(q[2], t0, t1, t2);
    }
    float ismc = ism[idx];
    out[((b * 3 + 0) << 12) + col] = __expf(t0) * ismc;
    out[((b * 3 + 1) << 12) + col] = __expf(t1) * ismc;
    out[((b * 3 + 2) << 12) + col] = __expf(t2) * ismc;
}

extern "C" void kernel_launch(void* const* d_in, const int* in_sizes, int n_in,
                              void* d_out, int out_size, void* d_ws, size_t ws_size,
                              hipStream_t stream) {
    const float* x = (const float*)d_in[0];
    const float* alpha = (const float*)d_in[1];
    float* out = (float*)d_out;
    char* ws = (char*)d_ws;
    bf16* xnT = (bf16*)ws;                                    // 8 MB
    float* ism = (float*)(ws + (8u << 20));                   // 64 KB
    float* lsm = (float*)(ws + (8u << 20) + (64u << 10));     // 64 KB
    // rpart (2 MB) and wtop (6 MB) share the same region: disjoint lifetimes
    // (rpart: rowsum->recip; wtop: topk->merge).
    float* rpart = (float*)(ws + (8u << 20) + (128u << 10));
    float* wtop  = (float*)(ws + (8u << 20) + (128u << 10));

    corr_norm<<<256, 256, 0, stream>>>(x, xnT);
    corr_rowsum<<<528 * 4, 256, 0, stream>>>(xnT, alpha, rpart);
    corr_recip<<<64, 256, 0, stream>>>(rpart, ism, lsm);
    corr_topk<<<1024 * 4, 256, 0, stream>>>(xnT, alpha, lsm, wtop);
    corr_merge<<<64, 256, 0, stream>>>(wtop, ism, out);
}